// Round 1
// baseline (336.188 us; speedup 1.0000x reference)
//
#include <hip/hip_runtime.h>

// Problem: fg/bg masked unbiased variance, Pred/GT fp32 [4096,1,100,100].
// Memory-bound: 327.7 MB read, 2 floats out. One-pass var:
//   var = (sumsq - n*mean^2) / (n-1), mean = sum/n  (exact rewrite of reference)
// Masks: fg = (GT > 0.5) && (Pred != 0); bg = (GT < 0.5) && (Pred != 0).

#define NSAMP   4096
#define ELEMS   10000           // 100*100 per sample
#define VECS    (ELEMS / 4)     // 2500 float4 per sample
#define BLOCK   256

__device__ __forceinline__ float wave_reduce_add(float v) {
    #pragma unroll
    for (int off = 32; off > 0; off >>= 1)
        v += __shfl_down(v, off, 64);
    return v;
}

__global__ __launch_bounds__(BLOCK) void stage1_persample(
        const float* __restrict__ Pred,
        const float* __restrict__ GT,
        float* __restrict__ vars /* [2][NSAMP]: fg then bg */) {
    const int b   = blockIdx.x;
    const int tid = threadIdx.x;

    const float4* __restrict__ p4 = (const float4*)(Pred + (size_t)b * ELEMS);
    const float4* __restrict__ g4 = (const float4*)(GT   + (size_t)b * ELEMS);

    float cfg = 0.f, sfg = 0.f, qfg = 0.f;
    float cbg = 0.f, sbg = 0.f, qbg = 0.f;

    for (int i = tid; i < VECS; i += BLOCK) {
        float4 p = p4[i];
        float4 g = g4[i];
        #pragma unroll
        for (int c = 0; c < 4; ++c) {
            float pp = (&p.x)[c];
            float gg = (&g.x)[c];
            float sq = pp * pp;
            bool  nz = (pp != 0.0f);
            float fg = (gg > 0.5f && nz) ? 1.0f : 0.0f;
            float bg = (gg < 0.5f && nz) ? 1.0f : 0.0f;
            cfg += fg;  sfg += fg * pp;  qfg += fg * sq;
            cbg += bg;  sbg += bg * pp;  qbg += bg * sq;
        }
    }

    // Block reduction: wave-64 shuffle tree, then LDS across the 4 waves.
    const int lane = tid & 63;
    const int wid  = tid >> 6;
    __shared__ float red[6][BLOCK / 64];

    float vals[6] = {cfg, sfg, qfg, cbg, sbg, qbg};
    #pragma unroll
    for (int k = 0; k < 6; ++k) {
        float r = wave_reduce_add(vals[k]);
        if (lane == 0) red[k][wid] = r;
    }
    __syncthreads();

    if (tid == 0) {
        float t[6];
        #pragma unroll
        for (int k = 0; k < 6; ++k) {
            float a = 0.f;
            #pragma unroll
            for (int w = 0; w < BLOCK / 64; ++w) a += red[k][w];
            t[k] = a;
        }
        // fg
        {
            float n    = t[0];
            float mean = t[1] / n;
            float var  = (t[2] - n * mean * mean) / (n - 1.0f);
            vars[b] = var;
        }
        // bg
        {
            float n    = t[3];
            float mean = t[4] / n;
            float var  = (t[5] - n * mean * mean) / (n - 1.0f);
            vars[NSAMP + b] = var;
        }
    }
}

__global__ __launch_bounds__(BLOCK) void stage2_mean(
        const float* __restrict__ vars,
        float* __restrict__ out) {
    const int tid = threadIdx.x;
    float sf = 0.f, sb = 0.f;
    for (int i = tid; i < NSAMP; i += BLOCK) {
        sf += vars[i];
        sb += vars[NSAMP + i];
    }
    const int lane = tid & 63;
    const int wid  = tid >> 6;
    __shared__ float red[2][BLOCK / 64];
    sf = wave_reduce_add(sf);
    sb = wave_reduce_add(sb);
    if (lane == 0) { red[0][wid] = sf; red[1][wid] = sb; }
    __syncthreads();
    if (tid == 0) {
        float a = 0.f, b2 = 0.f;
        #pragma unroll
        for (int w = 0; w < BLOCK / 64; ++w) { a += red[0][w]; b2 += red[1][w]; }
        out[0] = a  / (float)NSAMP;  // fg_var
        out[1] = b2 / (float)NSAMP;  // bg_var
    }
}

extern "C" void kernel_launch(void* const* d_in, const int* in_sizes, int n_in,
                              void* d_out, int out_size, void* d_ws, size_t ws_size,
                              hipStream_t stream) {
    const float* Pred = (const float*)d_in[0];
    const float* GT   = (const float*)d_in[1];
    float* out  = (float*)d_out;
    float* vars = (float*)d_ws;   // 2*NSAMP floats = 32 KB

    stage1_persample<<<NSAMP, BLOCK, 0, stream>>>(Pred, GT, vars);
    stage2_mean<<<1, BLOCK, 0, stream>>>(vars, out);
}

// Round 2
// 330.654 us; speedup vs baseline: 1.0167x; 1.0167x over previous
//
#include <hip/hip_runtime.h>

// fg/bg masked unbiased variance, Pred/GT fp32 [4096,1,100,100].
// Memory-bound: 327.7 MB read, 2 floats out.
// One-pass var: var = (sumsq - n*mean^2)/(n-1)  (exact rewrite of reference).
// Round 2 change: full unroll of the per-thread load loop (9 full + tail)
// into register arrays -> ~20 loads in flight per wave (was 2, VGPR=20,
// latency-bound at 43% of mem peak). Accumulation order unchanged
// (bit-identical to the passing round-1 kernel).

#define NSAMP   4096
#define ELEMS   10000           // 100*100 per sample
#define VECS    (ELEMS / 4)     // 2500 float4 per sample
#define BLOCK   256
#define FULL_IT 9               // 9*256 = 2304 vec4s
#define TAIL    (VECS - FULL_IT * BLOCK)   // 196

__device__ __forceinline__ float wave_reduce_add(float v) {
    #pragma unroll
    for (int off = 32; off > 0; off >>= 1)
        v += __shfl_down(v, off, 64);
    return v;
}

__global__ __launch_bounds__(BLOCK) void stage1_persample(
        const float* __restrict__ Pred,
        const float* __restrict__ GT,
        float* __restrict__ vars /* [2][NSAMP]: fg then bg */) {
    const int b   = blockIdx.x;
    const int tid = threadIdx.x;

    const float4* __restrict__ p4 = (const float4*)(Pred + (size_t)b * ELEMS);
    const float4* __restrict__ g4 = (const float4*)(GT   + (size_t)b * ELEMS);

    // ---- issue ALL loads up front (static indices -> registers) ----
    float4 pv[FULL_IT], gv[FULL_IT];
    #pragma unroll
    for (int i = 0; i < FULL_IT; ++i) {
        pv[i] = p4[tid + i * BLOCK];
        gv[i] = g4[tid + i * BLOCK];
    }
    const bool has_tail = (tid < TAIL);
    float4 pt, gt_;
    if (has_tail) {
        pt  = p4[FULL_IT * BLOCK + tid];
        gt_ = g4[FULL_IT * BLOCK + tid];
    }

    // ---- accumulate in the SAME per-thread order as round 1 ----
    float cfg = 0.f, sfg = 0.f, qfg = 0.f;
    float cbg = 0.f, sbg = 0.f, qbg = 0.f;

    #pragma unroll
    for (int i = 0; i < FULL_IT; ++i) {
        #pragma unroll
        for (int c = 0; c < 4; ++c) {
            float pp = (&pv[i].x)[c];
            float gg = (&gv[i].x)[c];
            float sq = pp * pp;
            bool  nz = (pp != 0.0f);
            float fg = (gg > 0.5f && nz) ? 1.0f : 0.0f;
            float bg = (gg < 0.5f && nz) ? 1.0f : 0.0f;
            cfg += fg;  sfg += fg * pp;  qfg += fg * sq;
            cbg += bg;  sbg += bg * pp;  qbg += bg * sq;
        }
    }
    if (has_tail) {
        #pragma unroll
        for (int c = 0; c < 4; ++c) {
            float pp = (&pt.x)[c];
            float gg = (&gt_.x)[c];
            float sq = pp * pp;
            bool  nz = (pp != 0.0f);
            float fg = (gg > 0.5f && nz) ? 1.0f : 0.0f;
            float bg = (gg < 0.5f && nz) ? 1.0f : 0.0f;
            cfg += fg;  sfg += fg * pp;  qfg += fg * sq;
            cbg += bg;  sbg += bg * pp;  qbg += bg * sq;
        }
    }

    // ---- block reduction: wave-64 shuffle tree, then LDS across 4 waves ----
    const int lane = tid & 63;
    const int wid  = tid >> 6;
    __shared__ float red[6][BLOCK / 64];

    float vals[6] = {cfg, sfg, qfg, cbg, sbg, qbg};
    #pragma unroll
    for (int k = 0; k < 6; ++k) {
        float r = wave_reduce_add(vals[k]);
        if (lane == 0) red[k][wid] = r;
    }
    __syncthreads();

    if (tid == 0) {
        float t[6];
        #pragma unroll
        for (int k = 0; k < 6; ++k) {
            float a = 0.f;
            #pragma unroll
            for (int w = 0; w < BLOCK / 64; ++w) a += red[k][w];
            t[k] = a;
        }
        {
            float n    = t[0];
            float mean = t[1] / n;
            vars[b] = (t[2] - n * mean * mean) / (n - 1.0f);
        }
        {
            float n    = t[3];
            float mean = t[4] / n;
            vars[NSAMP + b] = (t[5] - n * mean * mean) / (n - 1.0f);
        }
    }
}

__global__ __launch_bounds__(BLOCK) void stage2_mean(
        const float* __restrict__ vars,
        float* __restrict__ out) {
    const int tid = threadIdx.x;
    float sf = 0.f, sb = 0.f;
    for (int i = tid; i < NSAMP; i += BLOCK) {
        sf += vars[i];
        sb += vars[NSAMP + i];
    }
    const int lane = tid & 63;
    const int wid  = tid >> 6;
    __shared__ float red[2][BLOCK / 64];
    sf = wave_reduce_add(sf);
    sb = wave_reduce_add(sb);
    if (lane == 0) { red[0][wid] = sf; red[1][wid] = sb; }
    __syncthreads();
    if (tid == 0) {
        float a = 0.f, b2 = 0.f;
        #pragma unroll
        for (int w = 0; w < BLOCK / 64; ++w) { a += red[0][w]; b2 += red[1][w]; }
        out[0] = a  / (float)NSAMP;  // fg_var
        out[1] = b2 / (float)NSAMP;  // bg_var
    }
}

extern "C" void kernel_launch(void* const* d_in, const int* in_sizes, int n_in,
                              void* d_out, int out_size, void* d_ws, size_t ws_size,
                              hipStream_t stream) {
    const float* Pred = (const float*)d_in[0];
    const float* GT   = (const float*)d_in[1];
    float* out  = (float*)d_out;
    float* vars = (float*)d_ws;   // 2*NSAMP floats = 32 KB

    stage1_persample<<<NSAMP, BLOCK, 0, stream>>>(Pred, GT, vars);
    stage2_mean<<<1, BLOCK, 0, stream>>>(vars, out);
}